// Round 3
// baseline (202.811 us; speedup 1.0000x reference)
//
#include <hip/hip_runtime.h>

// Problem constants (from reference): B=8, N=128, D=256, C=3
#define BB 8
#define NN 128
#define DD 256
#define NF4 (DD / 4)   // 64 float4 per (b,n,m) row

// Pass 1: two blocks per (b,n), each streams 64 rows (64 KB) of s_e[b,n,:,:].
// 2048 blocks x 256 threads -> 8 blocks/CU, 32 waves/CU for latency hiding of
// the L3-warm stream. No barrier before the stream: lam_b is computed in the
// epilogue by wave 0 only (64-lane float4 butterfly over the 256 score vals).
__global__ __launch_bounds__(256) void pass1_kernel(
    const float4* __restrict__ se4,       // (B,N,N,D) as float4
    const float4* __restrict__ sv4,       // (B,N,D)   as float4
    const float*  __restrict__ se_score,  // (B,3,N)
    const int*    __restrict__ sub_graph, // (B,)
    const float*  __restrict__ num_node,  // (B,)
    float4* __restrict__ ws4)             // (B,N,2,D) partials as float4
{
    const int blk = blockIdx.x;       // 0..2047
    const int b   = blk >> 8;
    const int rr  = blk & 255;
    const int n   = rr >> 1;
    const int h   = rr & 1;           // which half of the m range
    const int tid = threadIdx.x;      // 0..255
    const int v   = tid & 63;         // float4 column (d/4)
    const int s   = tid >> 6;         // wave id 0..3

    // ---- main stream: reduce s_e[b,n, h*64 : h*64+64, :] over m
    const float4* __restrict__ p =
        se4 + ((size_t)(b * NN + n) * NN + h * 64) * NF4;

    float4 a0 = make_float4(0.f, 0.f, 0.f, 0.f);
    float4 a1 = make_float4(0.f, 0.f, 0.f, 0.f);
    #pragma unroll
    for (int m = s; m < 64; m += 8) {
        const float4 x = p[m * NF4 + v];
        const float4 y = p[(m + 4) * NF4 + v];
        a0.x += x.x; a0.y += x.y; a0.z += x.z; a0.w += x.w;
        a1.x += y.x; a1.y += y.y; a1.z += y.z; a1.w += y.w;
    }
    float4 a;
    a.x = a0.x + a1.x; a.y = a0.y + a1.y;
    a.z = a0.z + a1.z; a.w = a0.w + a1.w;

    __shared__ float4 sm[256];
    sm[tid] = a;
    __syncthreads();

    if (tid < 64) {
        const float4 t0 = sm[tid];
        const float4 t1 = sm[tid + 64];
        const float4 t2 = sm[tid + 128];
        const float4 t3 = sm[tid + 192];

        // lam_b: wave-0 butterfly over the 2N=256 score entries (64 float4)
        const float4* __restrict__ sc4 =
            (const float4*)(se_score + b * 3 * NN);
        const float4 q = sc4[tid];
        float lam = q.x + q.y + q.z + q.w;
        #pragma unroll
        for (int off = 32; off > 0; off >>= 1)
            lam += __shfl_xor(lam, off, 64);
        const float lam_b = lam + 1e-6f;

        // per-(b,n) weight (wave-uniform scalar loads, L2-hot)
        const float sc   = se_score[b * 3 * NN + n] + se_score[b * 3 * NN + NN + n];
        const float mask = (sub_graph[b] == n && n != 0) ? 1.0f : 0.0f;
        const float nnum = num_node[b];
        const float w    = (sc + mask) / (lam_b * nnum * nnum);

        float4 r;
        r.x = w * (t0.x + t1.x + t2.x + t3.x);
        r.y = w * (t0.y + t1.y + t2.y + t3.y);
        r.z = w * (t0.z + t1.z + t2.z + t3.z);
        r.w = w * (t0.w + t1.w + t2.w + t3.w);

        if (h == 0) {   // fold the N * s_v term into one half only
            const float4 sv = sv4[(size_t)(b * NN + n) * NF4 + v];
            r.x += w * 128.0f * sv.x;
            r.y += w * 128.0f * sv.y;
            r.z += w * 128.0f * sv.z;
            r.w += w * 128.0f * sv.w;
        }

        ws4[((size_t)(b * NN + n) * 2 + h) * NF4 + v] = r;  // coalesced 1 KB
    }
}

// Pass 2: out[b,d] = sum over 256 partial rows of ws[b,:,:,d]. 8 blocks x 256.
__global__ __launch_bounds__(256) void pass2_kernel(
    const float4* __restrict__ ws4,   // (B,N*2,D) as float4
    float4* __restrict__ out4)        // (B,D) as float4
{
    const int b    = blockIdx.x;
    const int tid  = threadIdx.x;
    const int v    = tid & 63;
    const int part = tid >> 6;        // 0..3

    const float4* __restrict__ p = ws4 + (size_t)b * (NN * 2) * NF4;

    float4 a = make_float4(0.f, 0.f, 0.f, 0.f);
    #pragma unroll 8
    for (int r = part * 64; r < part * 64 + 64; ++r) {
        const float4 x = p[r * NF4 + v];
        a.x += x.x; a.y += x.y; a.z += x.z; a.w += x.w;
    }

    __shared__ float4 sm[256];
    sm[tid] = a;
    __syncthreads();

    if (tid < 64) {
        const float4 t0 = sm[tid];
        const float4 t1 = sm[tid + 64];
        const float4 t2 = sm[tid + 128];
        const float4 t3 = sm[tid + 192];
        float4 r;
        r.x = t0.x + t1.x + t2.x + t3.x;
        r.y = t0.y + t1.y + t2.y + t3.y;
        r.z = t0.z + t1.z + t2.z + t3.z;
        r.w = t0.w + t1.w + t2.w + t3.w;
        out4[b * NF4 + v] = r;
    }
}

extern "C" void kernel_launch(void* const* d_in, const int* in_sizes, int n_in,
                              void* d_out, int out_size, void* d_ws, size_t ws_size,
                              hipStream_t stream) {
    const float* s_v       = (const float*)d_in[0];  // (B,N,D)
    const float* s_e       = (const float*)d_in[1];  // (B,N,N,D)
    const int*   sub_graph = (const int*)  d_in[2];  // (B,)
    const float* s_e_score = (const float*)d_in[3];  // (B,3,N)
    const float* num_node  = (const float*)d_in[4];  // (B,)
    float4* out4 = (float4*)d_out;                   // (B,1,D) fp32
    float4* ws4  = (float4*)d_ws;                    // B*N*2*D floats = 2 MB

    pass1_kernel<<<2 * BB * NN, 256, 0, stream>>>(
        (const float4*)s_e, (const float4*)s_v, s_e_score, sub_graph, num_node, ws4);
    pass2_kernel<<<BB, 256, 0, stream>>>(ws4, out4);
}